// Round 14
// baseline (297.659 us; speedup 1.0000x reference)
//
#include <hip/hip_runtime.h>
#include <hip/hip_bf16.h>

// Model dims (fixed by the reference)
#define S_DIM   6
#define H_DIM   20
#define F_INN   8
#define N_OUTC  20
#define G_DIM   32
#define D1_DIM  16
#define NGRAPH  512
#define CAP     32      // max fast-path rows per ECC block (LDS x1buf)

typedef short short8 __attribute__((ext_vector_type(8)));
typedef float floatx4 __attribute__((ext_vector_type(4)));

__device__ __forceinline__ unsigned short f2bf(float f) {
    unsigned u = __float_as_uint(f);
    return (unsigned short)((u + 0x8000u) >> 16);   // RTN (ties up)
}
__device__ __forceinline__ float bf2f(unsigned short s) {
    return __uint_as_float(((unsigned)s) << 16);
}
// packed f32x2 -> bf16x2 (hardware v_cvt_pk_bf16_f32 on gfx950)
__device__ __forceinline__ unsigned pk2bf(float a, float b) {
    union { __hip_bfloat162 b2; unsigned u; } cv;
    cv.b2 = __float22bfloat162_rn(make_float2(a, b));
    return cv.u;
}

// ---------------------------------------------------------------------------
// 1) hist (+ one-time B3f prep in the first 24 blocks): deg histogram only.
// ---------------------------------------------------------------------------
__global__ __launch_bounds__(256) void hist_kernel(
    const int* __restrict__ ei, int E, int* __restrict__ cnt,
    const float* __restrict__ w3, const float* __restrict__ b3,
    unsigned short* __restrict__ B3f)
{
    int i = blockIdx.x * 256 + threadIdx.x;
    if (i < 6144) {                      // fragment-ready B3 table
        int jj   = i & 7;
        int n    = (i >> 3) & 15;
        int quad = (i >> 7) & 3;
        int nt   = (i >> 9) & 1;
        int s    = i >> 10;
        int K = 32 * s + quad * 8 + jj;
        int o = n + 16 * nt;
        float v = 0.0f;
        if (o < N_OUTC) {
            if (K < 160)      v = w3[(K >> 3) * 160 + (K & 7) * N_OUTC + o];
            else if (K < 168) v = b3[(K - 160) * N_OUTC + o];
        }
        B3f[i] = f2bf(v);
    }
    if (i >= E) return;
    atomicAdd(&cnt[ei[i]], 1);
}

// ---------------------------------------------------------------------------
// 2a) Per-block sums of deg (coalesced)
// ---------------------------------------------------------------------------
__global__ __launch_bounds__(256) void scanA_kernel(
    const int* __restrict__ deg, int N, int* __restrict__ bsum)
{
    int i = blockIdx.x * 256 + threadIdx.x;
    int v = (i < N) ? deg[i] : 0;
#pragma unroll
    for (int d = 1; d < 64; d <<= 1) v += __shfl_down(v, d, 64);
    __shared__ int ws[4];
    int wid = threadIdx.x >> 6;
    if ((threadIdx.x & 63) == 0) ws[wid] = v;
    __syncthreads();
    if (threadIdx.x == 0) bsum[blockIdx.x] = ws[0] + ws[1] + ws[2] + ws[3];
}

// ---------------------------------------------------------------------------
// 2b) Apply: block offset from bsum, block-local scan -> rowptr + cursor copy
// ---------------------------------------------------------------------------
__global__ __launch_bounds__(256) void scanC_kernel(
    const int* __restrict__ deg, int N, const int* __restrict__ bsum, int nbl,
    int E, int* __restrict__ rowptr, int* __restrict__ cursor)
{
    __shared__ int ws[4];
    __shared__ int sboff;
    int t = threadIdx.x;
    {
        int v = (t < nbl && t < blockIdx.x) ? bsum[t] : 0;
#pragma unroll
        for (int d = 1; d < 64; d <<= 1) v += __shfl_down(v, d, 64);
        int wid = t >> 6;
        if ((t & 63) == 0) ws[wid] = v;
        __syncthreads();
        if (t == 0) sboff = ws[0] + ws[1] + ws[2] + ws[3];
        __syncthreads();
    }

    int i = blockIdx.x * 256 + t;
    int d0 = (i < N) ? deg[i] : 0;
    int v = d0;
#pragma unroll
    for (int d = 1; d < 64; d <<= 1) {
        int u = __shfl_up(v, d, 64);
        if ((t & 63) >= d) v += u;
    }
    __shared__ int ws2[4];
    int wid = t >> 6;
    if ((t & 63) == 63) ws2[wid] = v;
    __syncthreads();
    int woff = 0;
    for (int w = 0; w < wid; ++w) woff += ws2[w];
    if (i < N) {
        int rp = sboff + woff + v - d0;
        rowptr[i] = rp;
        cursor[i] = rp;          // build's slot cursor
    }
    if (blockIdx.x == 0 && t == 0) rowptr[N] = E;
}

// ---------------------------------------------------------------------------
// 3) Build slot-ordered edge records via cursor atomics:
//    p = atomicAdd(&cursor[r],1); e_sorted[p] = {col:int, e[6]:bf16} (16 B).
// ---------------------------------------------------------------------------
__global__ __launch_bounds__(256) void build_kernel(
    const int* __restrict__ ei, int E, const float* __restrict__ e,
    int* __restrict__ cursor, int4* __restrict__ e_sorted)
{
    int i = blockIdx.x * 256 + threadIdx.x;
    if (i >= E) return;
    int r = ei[i];
    int c = ei[E + i];
    int p = atomicAdd(&cursor[r], 1);

    const float2* ep = (const float2*)&e[(size_t)i * S_DIM];   // 8B-aligned
    float2 e0 = ep[0], e1 = ep[1], e2 = ep[2];

    int4 rec;
    rec.x = c;
    rec.y = (int)pk2bf(e0.x, e0.y);
    rec.z = (int)pk2bf(e1.x, e1.y);
    rec.w = (int)pk2bf(e2.x, e2.y);
    e_sorted[p] = rec;
}

// ---------------------------------------------------------------------------
// 4) ECC: MLP (fp32 VALU) -> MFMA einsum -> segmented reduce WITH FUSED
//    node1 transform for fully-owned rows. Boundary/overflow -> agg+cleanup.
//    Packed bf16 conversion (v_cvt_pk_bf16_f32) in all hot cvt paths.
// ---------------------------------------------------------------------------
__global__ __launch_bounds__(256) void ecc_mfma_kernel(
    const int4* __restrict__ e_sorted, const float* __restrict__ x,
    const int* __restrict__ rowptr, int N, int E,
    const unsigned short* __restrict__ B3f,
    const float* __restrict__ w1, const float* __restrict__ b1,
    const float* __restrict__ w2, const float* __restrict__ b2,
    const float* __restrict__ root, const float* __restrict__ eb,
    const float* __restrict__ g1w,
    float* __restrict__ agg, int* __restrict__ col_sorted,
    unsigned short* __restrict__ hws1)
{
    __shared__ char smem[20480];
    __shared__ float x1buf[CAP * N_OUTC];   // 2.5 KB
    __shared__ int rbounds[2];
    unsigned short (*h2b)[N_OUTC] = (unsigned short (*)[N_OUTC])smem;          // 10240
    unsigned short (*xb)[F_INN]   = (unsigned short (*)[F_INN])(smem + 10240); // 4096
    float* lmsg = (float*)smem;                                                // 20480

    int t = threadIdx.x;
    int j0 = blockIdx.x * 256;
    int jend = min(j0 + 256, E);
    int j = j0 + t;

    if (t < 2) {
        int s = (t == 0) ? j0 : (jend - 1);
        int lo = 0, hi = N - 1;
        while (lo < hi) {
            int m = (lo + hi + 1) >> 1;
            if (rowptr[m] <= s) lo = m; else hi = m - 1;
        }
        rbounds[t] = lo;
    }

    // ---- per-edge MLP (fp32), 16B coalesced edge record load ----
    if (j < E) {
        int4 rec = e_sorted[j];
        int c = rec.x;
        col_sorted[j] = c;
        float ef[S_DIM] = {
            bf2f((unsigned short)(rec.y & 0xffff)),
            bf2f((unsigned short)((unsigned)rec.y >> 16)),
            bf2f((unsigned short)(rec.z & 0xffff)),
            bf2f((unsigned short)((unsigned)rec.z >> 16)),
            bf2f((unsigned short)(rec.w & 0xffff)),
            bf2f((unsigned short)((unsigned)rec.w >> 16))
        };

        float h1[H_DIM];
#pragma unroll
        for (int jj = 0; jj < H_DIM; ++jj) {
            float a = b1[jj];
#pragma unroll
            for (int s = 0; s < S_DIM; ++s) a = fmaf(ef[s], w1[s * H_DIM + jj], a);
            h1[jj] = fmaxf(a, 0.0f);
        }

        float h2[H_DIM];
#pragma unroll
        for (int jj = 0; jj < H_DIM; ++jj) {
            float a = b2[jj];
#pragma unroll
            for (int k = 0; k < H_DIM; ++k) a = fmaf(h1[k], w2[k * H_DIM + jj], a);
            h2[jj] = fmaxf(a, 0.0f);
        }

        const float4* xp = (const float4*)&x[(size_t)c * F_INN];
        float4 xa = xp[0], xb4 = xp[1];
        float xf[F_INN] = {xa.x, xa.y, xa.z, xa.w, xb4.x, xb4.y, xb4.z, xb4.w};

#pragma unroll
        for (int p = 0; p < N_OUTC / 2; ++p)
            *(unsigned*)&h2b[t][2 * p] = pk2bf(h2[2 * p], h2[2 * p + 1]);
#pragma unroll
        for (int p = 0; p < F_INN / 2; ++p)
            *(unsigned*)&xb[t][2 * p] = pk2bf(xf[2 * p], xf[2 * p + 1]);
    } else {
#pragma unroll
        for (int p = 0; p < N_OUTC / 2; ++p) *(unsigned*)&h2b[t][2 * p] = 0u;
#pragma unroll
        for (int p = 0; p < F_INN / 2; ++p)  *(unsigned*)&xb[t][2 * p] = 0u;
    }
    __syncthreads();

    // ---- B fragments straight from global (hot in L1 after block 0) ----
    int lane = t & 63;
    int quad = lane >> 4;
    int n = lane & 15;
    const short8* Bg = (const short8*)B3f;
    short8 Bf[12];
#pragma unroll
    for (int s = 0; s < 6; ++s)
#pragma unroll
        for (int nt = 0; nt < 2; ++nt)
            Bf[s * 2 + nt] = Bg[((s * 2 + nt) * 4 + quad) * 16 + n];

    // ---- MFMA: 4 m-tiles per wave, accs in registers ----
    int w = t >> 6;
    floatx4 acc0s[4], acc1s[4];
#pragma unroll
    for (int T = 0; T < 4; ++T) {
        int base = w * 64 + T * 16;
        int m = base + n;

        const short8 xv8 = *(const short8*)&xb[m][0];
        float xfl[F_INN];
#pragma unroll
        for (int jj = 0; jj < F_INN; ++jj) xfl[jj] = bf2f((unsigned short)xv8[jj]);

        floatx4 acc0 = {0.f, 0.f, 0.f, 0.f};
        floatx4 acc1 = {0.f, 0.f, 0.f, 0.f};
#pragma unroll
        for (int s = 0; s < 6; ++s) {
            short8 A = {0, 0, 0, 0, 0, 0, 0, 0};
            if (s < 5) {
                float h = bf2f(h2b[m][4 * s + quad]);
                union { short8 s8; unsigned u[4]; } av;
#pragma unroll
                for (int p = 0; p < 4; ++p)
                    av.u[p] = pk2bf(h * xfl[2 * p], h * xfl[2 * p + 1]);
                A = av.s8;
            } else if (quad == 0) {
                A = xv8;                        // b3 rows: p = x
            }
            acc0 = __builtin_amdgcn_mfma_f32_16x16x32_bf16(A, Bf[s * 2 + 0], acc0, 0, 0, 0);
            acc1 = __builtin_amdgcn_mfma_f32_16x16x32_bf16(A, Bf[s * 2 + 1], acc1, 0, 0, 0);
        }
        acc0s[T] = acc0;
        acc1s[T] = acc1;
    }
    __syncthreads();   // staging reads done -> lmsg may alias

    // ---- C-write: col = n (+16 for acc1), row = base + quad*4 + r ----
#pragma unroll
    for (int T = 0; T < 4; ++T) {
        int base = w * 64 + T * 16;
#pragma unroll
        for (int r = 0; r < 4; ++r) {
            int row = base + quad * 4 + r;
            lmsg[row * N_OUTC + n] = acc0s[T][r];
            if (n < 4) lmsg[row * N_OUTC + 16 + n] = acc1s[T][r];
        }
    }
    __syncthreads();

    // ---- R1: segmented reduce; fused root+bias+relu for fast rows ----
    int r0 = rbounds[0], r1 = rbounds[1];
    int nrows = r1 - r0 + 1;
    int work = nrows * 5;
    for (int ww = t; ww < work; ww += 256) {
        int idx = ww / 5;
        int q = ww - idx * 5;
        int row = r0 + idx;
        int a0 = rowptr[row], a1 = rowptr[row + 1];
        int s0 = max(a0, j0), s1 = min(a1, jend);
        float ac0 = 0.f, ac1 = 0.f, ac2 = 0.f, ac3 = 0.f;
        for (int s = s0; s < s1; ++s) {
            const float4 v = *(const float4*)&lmsg[(s - j0) * N_OUTC + q * 4];
            ac0 += v.x; ac1 += v.y; ac2 += v.z; ac3 += v.w;
        }
        bool owned = (a0 >= j0 && a1 <= jend);
        if (owned && idx < CAP) {
            const float4* xp = (const float4*)&x[(size_t)row * F_INN];
            float4 xa = xp[0], xb4 = xp[1];
            float rx[F_INN] = {xa.x, xa.y, xa.z, xa.w, xb4.x, xb4.y, xb4.z, xb4.w};
            float av[4] = {ac0, ac1, ac2, ac3};
#pragma unroll
            for (int u = 0; u < 4; ++u) {
                int oc = q * 4 + u;
                float a = av[u] + eb[oc];
#pragma unroll
                for (int f = 0; f < F_INN; ++f)
                    a = fmaf(rx[f], root[f * N_OUTC + oc], a);
                x1buf[idx * N_OUTC + oc] = fmaxf(a, 0.0f);
            }
        } else {
            float* dst = &agg[(size_t)row * N_OUTC + q * 4];
            if (owned) {
                *(float4*)dst = make_float4(ac0, ac1, ac2, ac3);
            } else {
                unsafeAtomicAdd(dst + 0, ac0);
                unsafeAtomicAdd(dst + 1, ac1);
                unsafeAtomicAdd(dst + 2, ac2);
                unsafeAtomicAdd(dst + 3, ac3);
            }
        }
    }
    __syncthreads();

    // ---- R2: hws1 = bf16(dinv * (x1 @ g1w)) for fast rows ----
    int fast = min(nrows, CAP);
    int work2 = fast * 8;
    for (int ww = t; ww < work2; ww += 256) {
        int idx = ww >> 3;
        int qc = ww & 7;
        int row = r0 + idx;
        int a0 = rowptr[row], a1 = rowptr[row + 1];
        if (!(a0 >= j0 && a1 <= jend)) continue;
        float di = rsqrtf((float)(a1 - a0) + 1.0f);
        float m0 = 0.f, m1 = 0.f, m2 = 0.f, m3 = 0.f;
        const float* xr = &x1buf[idx * N_OUTC];
#pragma unroll
        for (int o = 0; o < N_OUTC; ++o) {
            float xv = xr[o];
            const float4 g = *(const float4*)&g1w[o * G_DIM + qc * 4];
            m0 = fmaf(xv, g.x, m0); m1 = fmaf(xv, g.y, m1);
            m2 = fmaf(xv, g.z, m2); m3 = fmaf(xv, g.w, m3);
        }
        unsigned lo32 = pk2bf(m0 * di, m1 * di);
        unsigned hi32 = pk2bf(m2 * di, m3 * di);
        *(uint2*)&hws1[(size_t)row * G_DIM + qc * 4] = make_uint2(lo32, hi32);
    }
}

// ---------------------------------------------------------------------------
// 5) Cleanup: node transform for rows NOT handled by ECC's fast path.
// ---------------------------------------------------------------------------
__global__ __launch_bounds__(256) void cleanup_kernel(
    const float* __restrict__ agg, const float* __restrict__ x,
    const int* __restrict__ rowptr, int N,
    const float* __restrict__ root, const float* __restrict__ eb,
    const float* __restrict__ g1w,
    unsigned short* __restrict__ hws1)
{
    int n = blockIdx.x * 256 + threadIdx.x;
    if (n >= N) return;
    int a0 = rowptr[n], a1 = rowptr[n + 1];
    bool contained = (a1 > a0) ? ((a0 >> 8) == ((a1 - 1) >> 8))
                               : ((a0 & 255) != 0);
    if (contained) {
        int target = (a0 >> 8) << 8;
        int lo = 0, hi = N - 1;
        while (lo < hi) {
            int m = (lo + hi + 1) >> 1;
            if (rowptr[m] <= target) lo = m; else hi = m - 1;
        }
        if (n - lo < CAP) return;          // handled inside ECC
    }

    const float4* xp = (const float4*)&x[(size_t)n * F_INN];
    float4 xa = xp[0], xb = xp[1];
    float xf[F_INN] = {xa.x, xa.y, xa.z, xa.w, xb.x, xb.y, xb.z, xb.w};

    float x1[N_OUTC];
#pragma unroll
    for (int o = 0; o < N_OUTC; ++o) {
        float a = agg[(size_t)n * N_OUTC + o] + eb[o];
#pragma unroll
        for (int f = 0; f < F_INN; ++f) a = fmaf(xf[f], root[f * N_OUTC + o], a);
        x1[o] = fmaxf(a, 0.0f);
    }

    float di = rsqrtf((float)(a1 - a0) + 1.0f);
#pragma unroll
    for (int q = 0; q < 4; ++q) {
        float a[8];
#pragma unroll
        for (int u = 0; u < 8; ++u) {
            int g = q * 8 + u;
            float acc = 0.0f;
#pragma unroll
            for (int o = 0; o < N_OUTC; ++o) acc = fmaf(x1[o], g1w[o * G_DIM + g], acc);
            a[u] = acc * di;
        }
        union { short8 s8; unsigned u4[4]; } ov;
#pragma unroll
        for (int p = 0; p < 4; ++p) ov.u4[p] = pk2bf(a[2 * p], a[2 * p + 1]);
        *(short8*)&hws1[(size_t)n * G_DIM + q * 8] = ov.s8;
    }
}

// ---------------------------------------------------------------------------
// 6) GCN gather on pre-scaled bf16 features. Thread = (node, chunk of 4);
//    neighbor loop manually unrolled x4 for deep load pipelining.
//    DO_MATMUL: fused @W2 -> hws2.  DO_POOL: per-block pool partials.
// ---------------------------------------------------------------------------
template<bool DO_MATMUL, bool DO_POOL>
__global__ __launch_bounds__(256) void gcn_gather_kernel(
    const unsigned short* __restrict__ hws, const int* __restrict__ rowptr,
    const int* __restrict__ col_sorted, const int* __restrict__ seg, int N,
    const float* __restrict__ bias, const float* __restrict__ w2,
    unsigned short* __restrict__ outbuf, float* __restrict__ pooled)
{
    __shared__ float x2s[DO_MATMUL ? 64 * 33 : 1];
    __shared__ float w2s[DO_MATMUL ? G_DIM * G_DIM : 1];
    __shared__ float pbuf[DO_POOL ? 64 * G_DIM : 1];     // 8 KB
    __shared__ int ginfo[2];

    int t = threadIdx.x;
    int n0 = blockIdx.x * 64;
    int nend = min(n0 + 64, N);

    if (DO_MATMUL) ((float4*)w2s)[t] = ((const float4*)w2)[t];
    if (DO_POOL) {
        if (t == 0) {
            int gmin = seg[n0];
            int gmax = seg[nend - 1];
            ginfo[0] = gmin;
            ginfo[1] = (gmax - gmin < 64) ? 1 : 0;
        }
        for (int k = t; k < 64 * G_DIM; k += 256) pbuf[k] = 0.0f;
    }
    if (DO_MATMUL || DO_POOL) __syncthreads();

    int nl = t >> 2;
    int q = t & 3;
    int n = n0 + nl;

    float xo[8];
    float di = 0.0f;
    if (n < N) {
        int j0 = rowptr[n], j1 = rowptr[n + 1];
        di = rsqrtf((float)(j1 - j0) + 1.0f);
        short8 sv = *(const short8*)&hws[(size_t)n * G_DIM + q * 8];
        float s[8];
#pragma unroll
        for (int k = 0; k < 8; ++k) s[k] = bf2f((unsigned short)sv[k]);
        int j = j0;
        for (; j + 4 <= j1; j += 4) {
            int c0 = col_sorted[j + 0];
            int c1 = col_sorted[j + 1];
            int c2 = col_sorted[j + 2];
            int c3 = col_sorted[j + 3];
            short8 v0 = *(const short8*)&hws[(size_t)c0 * G_DIM + q * 8];
            short8 v1 = *(const short8*)&hws[(size_t)c1 * G_DIM + q * 8];
            short8 v2 = *(const short8*)&hws[(size_t)c2 * G_DIM + q * 8];
            short8 v3 = *(const short8*)&hws[(size_t)c3 * G_DIM + q * 8];
#pragma unroll
            for (int k = 0; k < 8; ++k)
                s[k] += (bf2f((unsigned short)v0[k]) + bf2f((unsigned short)v1[k]))
                      + (bf2f((unsigned short)v2[k]) + bf2f((unsigned short)v3[k]));
        }
        for (; j < j1; ++j) {
            int c = col_sorted[j];
            short8 v = *(const short8*)&hws[(size_t)c * G_DIM + q * 8];
#pragma unroll
            for (int k = 0; k < 8; ++k) s[k] += bf2f((unsigned short)v[k]);
        }
#pragma unroll
        for (int k = 0; k < 8; ++k)
            xo[k] = fmaxf(fmaf(di, s[k], bias[q * 8 + k]), 0.0f);
    } else {
#pragma unroll
        for (int k = 0; k < 8; ++k) xo[k] = 0.0f;
    }

    if (DO_MATMUL) {
#pragma unroll
        for (int k = 0; k < 8; ++k) x2s[nl * 33 + q * 8 + k] = xo[k];
        __syncthreads();
        if (n < N) {
            float a[8];
#pragma unroll
            for (int k = 0; k < 8; ++k) a[k] = 0.0f;
#pragma unroll
            for (int g = 0; g < G_DIM; ++g) {
                float xv = x2s[nl * 33 + g];
#pragma unroll
                for (int k = 0; k < 8; ++k)
                    a[k] = fmaf(xv, w2s[g * G_DIM + q * 8 + k], a[k]);
            }
            union { short8 s8; unsigned u4[4]; } ov;
#pragma unroll
            for (int p = 0; p < 4; ++p) ov.u4[p] = pk2bf(a[2 * p] * di, a[2 * p + 1] * di);
            *(short8*)&outbuf[(size_t)n * G_DIM + q * 8] = ov.s8;
        }
    } else if (DO_POOL) {
        int gmin = ginfo[0];
        int use_lds = ginfo[1];
        if (n < N) {
            int sg = seg[n];
            if (use_lds) {
                float* base = &pbuf[(sg - gmin) * G_DIM + q * 8];
#pragma unroll
                for (int k = 0; k < 8; ++k) atomicAdd(&base[k], xo[k]);
            } else {
#pragma unroll
                for (int k = 0; k < 8; ++k)
                    unsafeAtomicAdd(&pooled[(size_t)sg * G_DIM + q * 8 + k], xo[k]);
            }
        }
        __syncthreads();
        if (use_lds) {
            for (int k = t; k < 64 * G_DIM; k += 256) {
                float v = pbuf[k];
                int g = gmin + (k >> 5);
                if (v != 0.0f && g < NGRAPH)
                    unsafeAtomicAdd(&pooled[(size_t)g * G_DIM + (k & 31)], v);
            }
        }
    } else {
        if (n < N) {
            union { short8 s8; unsigned u4[4]; } ov;
#pragma unroll
            for (int p = 0; p < 4; ++p) ov.u4[p] = pk2bf(xo[2 * p], xo[2 * p + 1]);
            *(short8*)&outbuf[(size_t)n * G_DIM + q * 8] = ov.s8;
        }
    }
}

// ---------------------------------------------------------------------------
// 7) Head: out = (pooled @ d1_w + d1_b) @ d2_w + d2_b
// ---------------------------------------------------------------------------
__global__ __launch_bounds__(256) void head_kernel(
    const float* __restrict__ pooled,
    const float* __restrict__ d1w, const float* __restrict__ d1b,
    const float* __restrict__ d2w, const float* __restrict__ d2b,
    float* __restrict__ out)
{
    int i = blockIdx.x * 256 + threadIdx.x;
    if (i >= NGRAPH) return;

    float p[G_DIM];
#pragma unroll
    for (int g = 0; g < G_DIM; ++g) p[g] = pooled[i * G_DIM + g];

    float acc = d2b[0];
#pragma unroll
    for (int j = 0; j < D1_DIM; ++j) {
        float tj = d1b[j];
#pragma unroll
        for (int g = 0; g < G_DIM; ++g) tj = fmaf(p[g], d1w[g * D1_DIM + j], tj);
        acc = fmaf(tj, d2w[j], acc);
    }
    out[i] = acc;
}

// ---------------------------------------------------------------------------
extern "C" void kernel_launch(void* const* d_in, const int* in_sizes, int n_in,
                              void* d_out, int out_size, void* d_ws, size_t ws_size,
                              hipStream_t stream)
{
    const float* x    = (const float*)d_in[0];
    const float* e    = (const float*)d_in[1];
    const int*   ei   = (const int*)d_in[2];
    const int*   seg  = (const int*)d_in[3];
    const float* w1   = (const float*)d_in[4];
    const float* b1   = (const float*)d_in[5];
    const float* w2   = (const float*)d_in[6];
    const float* b2   = (const float*)d_in[7];
    const float* w3   = (const float*)d_in[8];
    const float* b3   = (const float*)d_in[9];
    const float* root = (const float*)d_in[10];
    const float* eb   = (const float*)d_in[11];
    const float* g1w  = (const float*)d_in[12];
    const float* g1b  = (const float*)d_in[13];
    const float* g2w  = (const float*)d_in[14];
    const float* g2b  = (const float*)d_in[15];
    const float* d1w  = (const float*)d_in[16];
    const float* d1b  = (const float*)d_in[17];
    const float* d2w  = (const float*)d_in[18];
    const float* d2b  = (const float*)d_in[19];

    const int N = in_sizes[3];            // 50000
    const int E = in_sizes[1] / S_DIM;    // 800000
    float* out = (float*)d_out;

    const int nbl = (N + 255) / 256;      // 196 (<= 256 for scanC)
    const int ebl = (E + 255) / 256;

    char* ws = (char*)d_ws;
    size_t off = 0;
    auto alloc = [&](size_t elems) -> char* {
        char* p = ws + off;
        off += ((elems * 4 + 15) & ~(size_t)15);
        return p;
    };
    int*   cnt        = (int*)  alloc(N);                    // zeroed (deg)
    float* agg        = (float*)alloc((size_t)N * N_OUTC);   // zeroed
    float* pooled     = (float*)alloc(NGRAPH * G_DIM);       // zeroed
    size_t zero_bytes = off;
    int*   rowptr     = (int*)  alloc(N + 1);
    int*   cursor     = (int*)  alloc(N);
    int*   bsum       = (int*)  alloc(nbl);
    int*   col_sorted = (int*)  alloc(E);
    unsigned short* B3f = (unsigned short*)alloc(6144 / 2);  // 12.3 KB
    int4*  e_sorted   = (int4*) alloc((size_t)E * 4);        // 16 B/edge
    unsigned short* hws1 = (unsigned short*)alloc((size_t)N * G_DIM / 2);
    unsigned short* hws2 = (unsigned short*)alloc((size_t)N * G_DIM / 2);
    (void)ws_size;

    hipMemsetAsync(d_ws, 0, zero_bytes, stream);

    hist_kernel<<<ebl, 256, 0, stream>>>(ei, E, cnt, w3, b3, B3f);
    scanA_kernel<<<nbl, 256, 0, stream>>>(cnt, N, bsum);
    scanC_kernel<<<nbl, 256, 0, stream>>>(cnt, N, bsum, nbl, E, rowptr, cursor);
    build_kernel<<<ebl, 256, 0, stream>>>(ei, E, e, cursor, e_sorted);
    ecc_mfma_kernel<<<ebl, 256, 0, stream>>>(e_sorted, x, rowptr, N, E, B3f,
                                             w1, b1, w2, b2, root, eb, g1w,
                                             agg, col_sorted, hws1);
    cleanup_kernel<<<nbl, 256, 0, stream>>>(agg, x, rowptr, N, root, eb, g1w, hws1);
    gcn_gather_kernel<true, false><<<(N + 63) / 64, 256, 0, stream>>>(
        hws1, rowptr, col_sorted, seg, N, g1b, g2w, hws2, nullptr);
    gcn_gather_kernel<false, true><<<(N + 63) / 64, 256, 0, stream>>>(
        hws2, rowptr, col_sorted, seg, N, g2b, nullptr, nullptr, pooled);
    head_kernel<<<(NGRAPH + 255) / 256, 256, 0, stream>>>(pooled, d1w, d1b, d2w, d2b, out);
}

// Round 15
// 267.027 us; speedup vs baseline: 1.1147x; 1.1147x over previous
//
#include <hip/hip_runtime.h>
#include <hip/hip_bf16.h>

// Model dims (fixed by the reference)
#define S_DIM   6
#define H_DIM   20
#define F_INN   8
#define N_OUTC  20
#define G_DIM   32
#define D1_DIM  16
#define NGRAPH  512
#define CAP     32      // max fast-path rows per ECC block (LDS x1buf)

typedef short short8 __attribute__((ext_vector_type(8)));
typedef float floatx4 __attribute__((ext_vector_type(4)));

__device__ __forceinline__ unsigned short f2bf(float f) {
    unsigned u = __float_as_uint(f);
    return (unsigned short)((u + 0x8000u) >> 16);   // RTN (ties up)
}
__device__ __forceinline__ float bf2f(unsigned short s) {
    return __uint_as_float(((unsigned)s) << 16);
}
// packed f32x2 -> bf16x2 (hardware v_cvt_pk_bf16_f32 on gfx950)
__device__ __forceinline__ unsigned pk2bf(float a, float b) {
    union { __hip_bfloat162 b2; unsigned u; } cv;
    cv.b2 = __float22bfloat162_rn(make_float2(a, b));
    return cv.u;
}

// ---------------------------------------------------------------------------
// 1) loc (+ one-time B3f prep in first 24 blocks): ONE returning atomic per
//    edge; local slot stored coalesced in loc[]. cnt ends as deg[].
// ---------------------------------------------------------------------------
__global__ __launch_bounds__(256) void loc_kernel(
    const int* __restrict__ ei, int E, int* __restrict__ cnt,
    int* __restrict__ loc,
    const float* __restrict__ w3, const float* __restrict__ b3,
    unsigned short* __restrict__ B3f)
{
    int i = blockIdx.x * 256 + threadIdx.x;
    if (i < 6144) {                      // fragment-ready B3 table
        int jj   = i & 7;
        int n    = (i >> 3) & 15;
        int quad = (i >> 7) & 3;
        int nt   = (i >> 9) & 1;
        int s    = i >> 10;
        int K = 32 * s + quad * 8 + jj;
        int o = n + 16 * nt;
        float v = 0.0f;
        if (o < N_OUTC) {
            if (K < 160)      v = w3[(K >> 3) * 160 + (K & 7) * N_OUTC + o];
            else if (K < 168) v = b3[(K - 160) * N_OUTC + o];
        }
        B3f[i] = f2bf(v);
    }
    if (i >= E) return;
    loc[i] = atomicAdd(&cnt[ei[i]], 1);
}

// ---------------------------------------------------------------------------
// 2a) Per-block sums of deg (coalesced)
// ---------------------------------------------------------------------------
__global__ __launch_bounds__(256) void scanA_kernel(
    const int* __restrict__ deg, int N, int* __restrict__ bsum)
{
    int i = blockIdx.x * 256 + threadIdx.x;
    int v = (i < N) ? deg[i] : 0;
#pragma unroll
    for (int d = 1; d < 64; d <<= 1) v += __shfl_down(v, d, 64);
    __shared__ int ws[4];
    int wid = threadIdx.x >> 6;
    if ((threadIdx.x & 63) == 0) ws[wid] = v;
    __syncthreads();
    if (threadIdx.x == 0) bsum[blockIdx.x] = ws[0] + ws[1] + ws[2] + ws[3];
}

// ---------------------------------------------------------------------------
// 2b) Apply: block offset from bsum, block-local scan -> rowptr
// ---------------------------------------------------------------------------
__global__ __launch_bounds__(256) void scanC_kernel(
    const int* __restrict__ deg, int N, const int* __restrict__ bsum, int nbl,
    int E, int* __restrict__ rowptr)
{
    __shared__ int ws[4];
    __shared__ int sboff;
    int t = threadIdx.x;
    {
        int v = (t < nbl && t < blockIdx.x) ? bsum[t] : 0;
#pragma unroll
        for (int d = 1; d < 64; d <<= 1) v += __shfl_down(v, d, 64);
        int wid = t >> 6;
        if ((t & 63) == 0) ws[wid] = v;
        __syncthreads();
        if (t == 0) sboff = ws[0] + ws[1] + ws[2] + ws[3];
        __syncthreads();
    }

    int i = blockIdx.x * 256 + t;
    int d0 = (i < N) ? deg[i] : 0;
    int v = d0;
#pragma unroll
    for (int d = 1; d < 64; d <<= 1) {
        int u = __shfl_up(v, d, 64);
        if ((t & 63) >= d) v += u;
    }
    __shared__ int ws2[4];
    int wid = t >> 6;
    if ((t & 63) == 63) ws2[wid] = v;
    __syncthreads();
    int woff = 0;
    for (int w = 0; w < wid; ++w) woff += ws2[w];
    if (i < N) rowptr[i] = sboff + woff + v - d0;
    if (blockIdx.x == 0 && t == 0) rowptr[N] = E;
}

// ---------------------------------------------------------------------------
// 3) Build slot-ordered edge records (NO atomics: p = rowptr[r] + loc[i]):
//    e_sorted[p] = {col:int, e[6]:bf16} = 16 B, one scattered store per edge.
// ---------------------------------------------------------------------------
__global__ __launch_bounds__(256) void build_kernel(
    const int* __restrict__ ei, int E, const float* __restrict__ e,
    const int* __restrict__ rowptr, const int* __restrict__ loc,
    int4* __restrict__ e_sorted)
{
    int i = blockIdx.x * 256 + threadIdx.x;
    if (i >= E) return;
    int r = ei[i];
    int c = ei[E + i];
    int p = rowptr[r] + loc[i];

    const float2* ep = (const float2*)&e[(size_t)i * S_DIM];   // 8B-aligned
    float2 e0 = ep[0], e1 = ep[1], e2 = ep[2];

    int4 rec;
    rec.x = c;
    rec.y = (int)pk2bf(e0.x, e0.y);
    rec.z = (int)pk2bf(e1.x, e1.y);
    rec.w = (int)pk2bf(e2.x, e2.y);
    e_sorted[p] = rec;
}

// ---------------------------------------------------------------------------
// 4) ECC: MLP (fp32 VALU) -> MFMA einsum -> segmented reduce WITH FUSED
//    node1 transform for fully-owned rows. Boundary/overflow -> agg+cleanup.
//    Packed bf16 conversion (v_cvt_pk_bf16_f32) in all hot cvt paths.
// ---------------------------------------------------------------------------
__global__ __launch_bounds__(256) void ecc_mfma_kernel(
    const int4* __restrict__ e_sorted, const float* __restrict__ x,
    const int* __restrict__ rowptr, int N, int E,
    const unsigned short* __restrict__ B3f,
    const float* __restrict__ w1, const float* __restrict__ b1,
    const float* __restrict__ w2, const float* __restrict__ b2,
    const float* __restrict__ root, const float* __restrict__ eb,
    const float* __restrict__ g1w,
    float* __restrict__ agg, int* __restrict__ col_sorted,
    unsigned short* __restrict__ hws1)
{
    __shared__ char smem[20480];
    __shared__ float x1buf[CAP * N_OUTC];   // 2.5 KB
    __shared__ int rbounds[2];
    unsigned short (*h2b)[N_OUTC] = (unsigned short (*)[N_OUTC])smem;          // 10240
    unsigned short (*xb)[F_INN]   = (unsigned short (*)[F_INN])(smem + 10240); // 4096
    float* lmsg = (float*)smem;                                                // 20480

    int t = threadIdx.x;
    int j0 = blockIdx.x * 256;
    int jend = min(j0 + 256, E);
    int j = j0 + t;

    if (t < 2) {
        int s = (t == 0) ? j0 : (jend - 1);
        int lo = 0, hi = N - 1;
        while (lo < hi) {
            int m = (lo + hi + 1) >> 1;
            if (rowptr[m] <= s) lo = m; else hi = m - 1;
        }
        rbounds[t] = lo;
    }

    // ---- per-edge MLP (fp32), 16B coalesced edge record load ----
    if (j < E) {
        int4 rec = e_sorted[j];
        int c = rec.x;
        col_sorted[j] = c;
        float ef[S_DIM] = {
            bf2f((unsigned short)(rec.y & 0xffff)),
            bf2f((unsigned short)((unsigned)rec.y >> 16)),
            bf2f((unsigned short)(rec.z & 0xffff)),
            bf2f((unsigned short)((unsigned)rec.z >> 16)),
            bf2f((unsigned short)(rec.w & 0xffff)),
            bf2f((unsigned short)((unsigned)rec.w >> 16))
        };

        float h1[H_DIM];
#pragma unroll
        for (int jj = 0; jj < H_DIM; ++jj) {
            float a = b1[jj];
#pragma unroll
            for (int s = 0; s < S_DIM; ++s) a = fmaf(ef[s], w1[s * H_DIM + jj], a);
            h1[jj] = fmaxf(a, 0.0f);
        }

        float h2[H_DIM];
#pragma unroll
        for (int jj = 0; jj < H_DIM; ++jj) {
            float a = b2[jj];
#pragma unroll
            for (int k = 0; k < H_DIM; ++k) a = fmaf(h1[k], w2[k * H_DIM + jj], a);
            h2[jj] = fmaxf(a, 0.0f);
        }

        const float4* xp = (const float4*)&x[(size_t)c * F_INN];
        float4 xa = xp[0], xb4 = xp[1];
        float xf[F_INN] = {xa.x, xa.y, xa.z, xa.w, xb4.x, xb4.y, xb4.z, xb4.w};

#pragma unroll
        for (int p = 0; p < N_OUTC / 2; ++p)
            *(unsigned*)&h2b[t][2 * p] = pk2bf(h2[2 * p], h2[2 * p + 1]);
#pragma unroll
        for (int p = 0; p < F_INN / 2; ++p)
            *(unsigned*)&xb[t][2 * p] = pk2bf(xf[2 * p], xf[2 * p + 1]);
    } else {
#pragma unroll
        for (int p = 0; p < N_OUTC / 2; ++p) *(unsigned*)&h2b[t][2 * p] = 0u;
#pragma unroll
        for (int p = 0; p < F_INN / 2; ++p)  *(unsigned*)&xb[t][2 * p] = 0u;
    }
    __syncthreads();

    // ---- B fragments straight from global (hot in L1 after block 0) ----
    int lane = t & 63;
    int quad = lane >> 4;
    int n = lane & 15;
    const short8* Bg = (const short8*)B3f;
    short8 Bf[12];
#pragma unroll
    for (int s = 0; s < 6; ++s)
#pragma unroll
        for (int nt = 0; nt < 2; ++nt)
            Bf[s * 2 + nt] = Bg[((s * 2 + nt) * 4 + quad) * 16 + n];

    // ---- MFMA: 4 m-tiles per wave, accs in registers ----
    int w = t >> 6;
    floatx4 acc0s[4], acc1s[4];
#pragma unroll
    for (int T = 0; T < 4; ++T) {
        int base = w * 64 + T * 16;
        int m = base + n;

        const short8 xv8 = *(const short8*)&xb[m][0];
        float xfl[F_INN];
#pragma unroll
        for (int jj = 0; jj < F_INN; ++jj) xfl[jj] = bf2f((unsigned short)xv8[jj]);

        floatx4 acc0 = {0.f, 0.f, 0.f, 0.f};
        floatx4 acc1 = {0.f, 0.f, 0.f, 0.f};
#pragma unroll
        for (int s = 0; s < 6; ++s) {
            short8 A = {0, 0, 0, 0, 0, 0, 0, 0};
            if (s < 5) {
                float h = bf2f(h2b[m][4 * s + quad]);
                union { short8 s8; unsigned u[4]; } av;
#pragma unroll
                for (int p = 0; p < 4; ++p)
                    av.u[p] = pk2bf(h * xfl[2 * p], h * xfl[2 * p + 1]);
                A = av.s8;
            } else if (quad == 0) {
                A = xv8;                        // b3 rows: p = x
            }
            acc0 = __builtin_amdgcn_mfma_f32_16x16x32_bf16(A, Bf[s * 2 + 0], acc0, 0, 0, 0);
            acc1 = __builtin_amdgcn_mfma_f32_16x16x32_bf16(A, Bf[s * 2 + 1], acc1, 0, 0, 0);
        }
        acc0s[T] = acc0;
        acc1s[T] = acc1;
    }
    __syncthreads();   // staging reads done -> lmsg may alias

    // ---- C-write: col = n (+16 for acc1), row = base + quad*4 + r ----
#pragma unroll
    for (int T = 0; T < 4; ++T) {
        int base = w * 64 + T * 16;
#pragma unroll
        for (int r = 0; r < 4; ++r) {
            int row = base + quad * 4 + r;
            lmsg[row * N_OUTC + n] = acc0s[T][r];
            if (n < 4) lmsg[row * N_OUTC + 16 + n] = acc1s[T][r];
        }
    }
    __syncthreads();

    // ---- R1: segmented reduce; fused root+bias+relu for fast rows ----
    int r0 = rbounds[0], r1 = rbounds[1];
    int nrows = r1 - r0 + 1;
    int work = nrows * 5;
    for (int ww = t; ww < work; ww += 256) {
        int idx = ww / 5;
        int q = ww - idx * 5;
        int row = r0 + idx;
        int a0 = rowptr[row], a1 = rowptr[row + 1];
        int s0 = max(a0, j0), s1 = min(a1, jend);
        float ac0 = 0.f, ac1 = 0.f, ac2 = 0.f, ac3 = 0.f;
        for (int s = s0; s < s1; ++s) {
            const float4 v = *(const float4*)&lmsg[(s - j0) * N_OUTC + q * 4];
            ac0 += v.x; ac1 += v.y; ac2 += v.z; ac3 += v.w;
        }
        bool owned = (a0 >= j0 && a1 <= jend);
        if (owned && idx < CAP) {
            const float4* xp = (const float4*)&x[(size_t)row * F_INN];
            float4 xa = xp[0], xb4 = xp[1];
            float rx[F_INN] = {xa.x, xa.y, xa.z, xa.w, xb4.x, xb4.y, xb4.z, xb4.w};
            float av[4] = {ac0, ac1, ac2, ac3};
#pragma unroll
            for (int u = 0; u < 4; ++u) {
                int oc = q * 4 + u;
                float a = av[u] + eb[oc];
#pragma unroll
                for (int f = 0; f < F_INN; ++f)
                    a = fmaf(rx[f], root[f * N_OUTC + oc], a);
                x1buf[idx * N_OUTC + oc] = fmaxf(a, 0.0f);
            }
        } else {
            float* dst = &agg[(size_t)row * N_OUTC + q * 4];
            if (owned) {
                *(float4*)dst = make_float4(ac0, ac1, ac2, ac3);
            } else {
                unsafeAtomicAdd(dst + 0, ac0);
                unsafeAtomicAdd(dst + 1, ac1);
                unsafeAtomicAdd(dst + 2, ac2);
                unsafeAtomicAdd(dst + 3, ac3);
            }
        }
    }
    __syncthreads();

    // ---- R2: hws1 = bf16(dinv * (x1 @ g1w)) for fast rows ----
    int fast = min(nrows, CAP);
    int work2 = fast * 8;
    for (int ww = t; ww < work2; ww += 256) {
        int idx = ww >> 3;
        int qc = ww & 7;
        int row = r0 + idx;
        int a0 = rowptr[row], a1 = rowptr[row + 1];
        if (!(a0 >= j0 && a1 <= jend)) continue;
        float di = rsqrtf((float)(a1 - a0) + 1.0f);
        float m0 = 0.f, m1 = 0.f, m2 = 0.f, m3 = 0.f;
        const float* xr = &x1buf[idx * N_OUTC];
#pragma unroll
        for (int o = 0; o < N_OUTC; ++o) {
            float xv = xr[o];
            const float4 g = *(const float4*)&g1w[o * G_DIM + qc * 4];
            m0 = fmaf(xv, g.x, m0); m1 = fmaf(xv, g.y, m1);
            m2 = fmaf(xv, g.z, m2); m3 = fmaf(xv, g.w, m3);
        }
        unsigned lo32 = pk2bf(m0 * di, m1 * di);
        unsigned hi32 = pk2bf(m2 * di, m3 * di);
        *(uint2*)&hws1[(size_t)row * G_DIM + qc * 4] = make_uint2(lo32, hi32);
    }
}

// ---------------------------------------------------------------------------
// 5) Cleanup: node transform for rows NOT handled by ECC's fast path.
// ---------------------------------------------------------------------------
__global__ __launch_bounds__(256) void cleanup_kernel(
    const float* __restrict__ agg, const float* __restrict__ x,
    const int* __restrict__ rowptr, int N,
    const float* __restrict__ root, const float* __restrict__ eb,
    const float* __restrict__ g1w,
    unsigned short* __restrict__ hws1)
{
    int n = blockIdx.x * 256 + threadIdx.x;
    if (n >= N) return;
    int a0 = rowptr[n], a1 = rowptr[n + 1];
    bool contained = (a1 > a0) ? ((a0 >> 8) == ((a1 - 1) >> 8))
                               : ((a0 & 255) != 0);
    if (contained) {
        int target = (a0 >> 8) << 8;
        int lo = 0, hi = N - 1;
        while (lo < hi) {
            int m = (lo + hi + 1) >> 1;
            if (rowptr[m] <= target) lo = m; else hi = m - 1;
        }
        if (n - lo < CAP) return;          // handled inside ECC
    }

    const float4* xp = (const float4*)&x[(size_t)n * F_INN];
    float4 xa = xp[0], xb = xp[1];
    float xf[F_INN] = {xa.x, xa.y, xa.z, xa.w, xb.x, xb.y, xb.z, xb.w};

    float x1[N_OUTC];
#pragma unroll
    for (int o = 0; o < N_OUTC; ++o) {
        float a = agg[(size_t)n * N_OUTC + o] + eb[o];
#pragma unroll
        for (int f = 0; f < F_INN; ++f) a = fmaf(xf[f], root[f * N_OUTC + o], a);
        x1[o] = fmaxf(a, 0.0f);
    }

    float di = rsqrtf((float)(a1 - a0) + 1.0f);
#pragma unroll
    for (int q = 0; q < 4; ++q) {
        float a[8];
#pragma unroll
        for (int u = 0; u < 8; ++u) {
            int g = q * 8 + u;
            float acc = 0.0f;
#pragma unroll
            for (int o = 0; o < N_OUTC; ++o) acc = fmaf(x1[o], g1w[o * G_DIM + g], acc);
            a[u] = acc * di;
        }
        union { short8 s8; unsigned u4[4]; } ov;
#pragma unroll
        for (int p = 0; p < 4; ++p) ov.u4[p] = pk2bf(a[2 * p], a[2 * p + 1]);
        *(short8*)&hws1[(size_t)n * G_DIM + q * 8] = ov.s8;
    }
}

// ---------------------------------------------------------------------------
// 6) GCN gather on pre-scaled bf16 features. Thread = (node, chunk of 4);
//    neighbor loop manually unrolled x4 for deep load pipelining.
//    DO_MATMUL: fused @W2 -> hws2.  DO_POOL: per-block pool partials.
// ---------------------------------------------------------------------------
template<bool DO_MATMUL, bool DO_POOL>
__global__ __launch_bounds__(256) void gcn_gather_kernel(
    const unsigned short* __restrict__ hws, const int* __restrict__ rowptr,
    const int* __restrict__ col_sorted, const int* __restrict__ seg, int N,
    const float* __restrict__ bias, const float* __restrict__ w2,
    unsigned short* __restrict__ outbuf, float* __restrict__ pooled)
{
    __shared__ float x2s[DO_MATMUL ? 64 * 33 : 1];
    __shared__ float w2s[DO_MATMUL ? G_DIM * G_DIM : 1];
    __shared__ float pbuf[DO_POOL ? 64 * G_DIM : 1];     // 8 KB
    __shared__ int ginfo[2];

    int t = threadIdx.x;
    int n0 = blockIdx.x * 64;
    int nend = min(n0 + 64, N);

    if (DO_MATMUL) ((float4*)w2s)[t] = ((const float4*)w2)[t];
    if (DO_POOL) {
        if (t == 0) {
            int gmin = seg[n0];
            int gmax = seg[nend - 1];
            ginfo[0] = gmin;
            ginfo[1] = (gmax - gmin < 64) ? 1 : 0;
        }
        for (int k = t; k < 64 * G_DIM; k += 256) pbuf[k] = 0.0f;
    }
    if (DO_MATMUL || DO_POOL) __syncthreads();

    int nl = t >> 2;
    int q = t & 3;
    int n = n0 + nl;

    float xo[8];
    float di = 0.0f;
    if (n < N) {
        int j0 = rowptr[n], j1 = rowptr[n + 1];
        di = rsqrtf((float)(j1 - j0) + 1.0f);
        short8 sv = *(const short8*)&hws[(size_t)n * G_DIM + q * 8];
        float s[8];
#pragma unroll
        for (int k = 0; k < 8; ++k) s[k] = bf2f((unsigned short)sv[k]);
        int j = j0;
        for (; j + 4 <= j1; j += 4) {
            int c0 = col_sorted[j + 0];
            int c1 = col_sorted[j + 1];
            int c2 = col_sorted[j + 2];
            int c3 = col_sorted[j + 3];
            short8 v0 = *(const short8*)&hws[(size_t)c0 * G_DIM + q * 8];
            short8 v1 = *(const short8*)&hws[(size_t)c1 * G_DIM + q * 8];
            short8 v2 = *(const short8*)&hws[(size_t)c2 * G_DIM + q * 8];
            short8 v3 = *(const short8*)&hws[(size_t)c3 * G_DIM + q * 8];
#pragma unroll
            for (int k = 0; k < 8; ++k)
                s[k] += (bf2f((unsigned short)v0[k]) + bf2f((unsigned short)v1[k]))
                      + (bf2f((unsigned short)v2[k]) + bf2f((unsigned short)v3[k]));
        }
        for (; j < j1; ++j) {
            int c = col_sorted[j];
            short8 v = *(const short8*)&hws[(size_t)c * G_DIM + q * 8];
#pragma unroll
            for (int k = 0; k < 8; ++k) s[k] += bf2f((unsigned short)v[k]);
        }
#pragma unroll
        for (int k = 0; k < 8; ++k)
            xo[k] = fmaxf(fmaf(di, s[k], bias[q * 8 + k]), 0.0f);
    } else {
#pragma unroll
        for (int k = 0; k < 8; ++k) xo[k] = 0.0f;
    }

    if (DO_MATMUL) {
#pragma unroll
        for (int k = 0; k < 8; ++k) x2s[nl * 33 + q * 8 + k] = xo[k];
        __syncthreads();
        if (n < N) {
            float a[8];
#pragma unroll
            for (int k = 0; k < 8; ++k) a[k] = 0.0f;
#pragma unroll
            for (int g = 0; g < G_DIM; ++g) {
                float xv = x2s[nl * 33 + g];
#pragma unroll
                for (int k = 0; k < 8; ++k)
                    a[k] = fmaf(xv, w2s[g * G_DIM + q * 8 + k], a[k]);
            }
            union { short8 s8; unsigned u4[4]; } ov;
#pragma unroll
            for (int p = 0; p < 4; ++p) ov.u4[p] = pk2bf(a[2 * p] * di, a[2 * p + 1] * di);
            *(short8*)&outbuf[(size_t)n * G_DIM + q * 8] = ov.s8;
        }
    } else if (DO_POOL) {
        int gmin = ginfo[0];
        int use_lds = ginfo[1];
        if (n < N) {
            int sg = seg[n];
            if (use_lds) {
                float* base = &pbuf[(sg - gmin) * G_DIM + q * 8];
#pragma unroll
                for (int k = 0; k < 8; ++k) atomicAdd(&base[k], xo[k]);
            } else {
#pragma unroll
                for (int k = 0; k < 8; ++k)
                    unsafeAtomicAdd(&pooled[(size_t)sg * G_DIM + q * 8 + k], xo[k]);
            }
        }
        __syncthreads();
        if (use_lds) {
            for (int k = t; k < 64 * G_DIM; k += 256) {
                float v = pbuf[k];
                int g = gmin + (k >> 5);
                if (v != 0.0f && g < NGRAPH)
                    unsafeAtomicAdd(&pooled[(size_t)g * G_DIM + (k & 31)], v);
            }
        }
    } else {
        if (n < N) {
            union { short8 s8; unsigned u4[4]; } ov;
#pragma unroll
            for (int p = 0; p < 4; ++p) ov.u4[p] = pk2bf(xo[2 * p], xo[2 * p + 1]);
            *(short8*)&outbuf[(size_t)n * G_DIM + q * 8] = ov.s8;
        }
    }
}

// ---------------------------------------------------------------------------
// 7) Head: out = (pooled @ d1_w + d1_b) @ d2_w + d2_b
// ---------------------------------------------------------------------------
__global__ __launch_bounds__(256) void head_kernel(
    const float* __restrict__ pooled,
    const float* __restrict__ d1w, const float* __restrict__ d1b,
    const float* __restrict__ d2w, const float* __restrict__ d2b,
    float* __restrict__ out)
{
    int i = blockIdx.x * 256 + threadIdx.x;
    if (i >= NGRAPH) return;

    float p[G_DIM];
#pragma unroll
    for (int g = 0; g < G_DIM; ++g) p[g] = pooled[i * G_DIM + g];

    float acc = d2b[0];
#pragma unroll
    for (int j = 0; j < D1_DIM; ++j) {
        float tj = d1b[j];
#pragma unroll
        for (int g = 0; g < G_DIM; ++g) tj = fmaf(p[g], d1w[g * D1_DIM + j], tj);
        acc = fmaf(tj, d2w[j], acc);
    }
    out[i] = acc;
}

// ---------------------------------------------------------------------------
extern "C" void kernel_launch(void* const* d_in, const int* in_sizes, int n_in,
                              void* d_out, int out_size, void* d_ws, size_t ws_size,
                              hipStream_t stream)
{
    const float* x    = (const float*)d_in[0];
    const float* e    = (const float*)d_in[1];
    const int*   ei   = (const int*)d_in[2];
    const int*   seg  = (const int*)d_in[3];
    const float* w1   = (const float*)d_in[4];
    const float* b1   = (const float*)d_in[5];
    const float* w2   = (const float*)d_in[6];
    const float* b2   = (const float*)d_in[7];
    const float* w3   = (const float*)d_in[8];
    const float* b3   = (const float*)d_in[9];
    const float* root = (const float*)d_in[10];
    const float* eb   = (const float*)d_in[11];
    const float* g1w  = (const float*)d_in[12];
    const float* g1b  = (const float*)d_in[13];
    const float* g2w  = (const float*)d_in[14];
    const float* g2b  = (const float*)d_in[15];
    const float* d1w  = (const float*)d_in[16];
    const float* d1b  = (const float*)d_in[17];
    const float* d2w  = (const float*)d_in[18];
    const float* d2b  = (const float*)d_in[19];

    const int N = in_sizes[3];            // 50000
    const int E = in_sizes[1] / S_DIM;    // 800000
    float* out = (float*)d_out;

    const int nbl = (N + 255) / 256;      // 196 (<= 256 for scanC)
    const int ebl = (E + 255) / 256;

    char* ws = (char*)d_ws;
    size_t off = 0;
    auto alloc = [&](size_t elems) -> char* {
        char* p = ws + off;
        off += ((elems * 4 + 15) & ~(size_t)15);
        return p;
    };
    int*   cnt        = (int*)  alloc(N);                    // zeroed (deg)
    float* agg        = (float*)alloc((size_t)N * N_OUTC);   // zeroed
    float* pooled     = (float*)alloc(NGRAPH * G_DIM);       // zeroed
    size_t zero_bytes = off;
    int*   rowptr     = (int*)  alloc(N + 1);
    int*   bsum       = (int*)  alloc(nbl);
    int*   loc        = (int*)  alloc(E);
    int*   col_sorted = (int*)  alloc(E);
    unsigned short* B3f = (unsigned short*)alloc(6144 / 2);  // 12.3 KB
    int4*  e_sorted   = (int4*) alloc((size_t)E * 4);        // 16 B/edge
    unsigned short* hws1 = (unsigned short*)alloc((size_t)N * G_DIM / 2);
    unsigned short* hws2 = (unsigned short*)alloc((size_t)N * G_DIM / 2);
    (void)ws_size;

    hipMemsetAsync(d_ws, 0, zero_bytes, stream);

    loc_kernel<<<ebl, 256, 0, stream>>>(ei, E, cnt, loc, w3, b3, B3f);
    scanA_kernel<<<nbl, 256, 0, stream>>>(cnt, N, bsum);
    scanC_kernel<<<nbl, 256, 0, stream>>>(cnt, N, bsum, nbl, E, rowptr);
    build_kernel<<<ebl, 256, 0, stream>>>(ei, E, e, rowptr, loc, e_sorted);
    ecc_mfma_kernel<<<ebl, 256, 0, stream>>>(e_sorted, x, rowptr, N, E, B3f,
                                             w1, b1, w2, b2, root, eb, g1w,
                                             agg, col_sorted, hws1);
    cleanup_kernel<<<nbl, 256, 0, stream>>>(agg, x, rowptr, N, root, eb, g1w, hws1);
    gcn_gather_kernel<true, false><<<(N + 63) / 64, 256, 0, stream>>>(
        hws1, rowptr, col_sorted, seg, N, g1b, g2w, hws2, nullptr);
    gcn_gather_kernel<false, true><<<(N + 63) / 64, 256, 0, stream>>>(
        hws2, rowptr, col_sorted, seg, N, g2b, nullptr, nullptr, pooled);
    head_kernel<<<(NGRAPH + 255) / 256, 256, 0, stream>>>(pooled, d1w, d1b, d2w, d2b, out);
}

// Round 16
// 262.564 us; speedup vs baseline: 1.1337x; 1.0170x over previous
//
#include <hip/hip_runtime.h>
#include <hip/hip_bf16.h>

// Model dims (fixed by the reference)
#define S_DIM   6
#define H_DIM   20
#define F_INN   8
#define N_OUTC  20
#define G_DIM   32
#define D1_DIM  16
#define NGRAPH  512
#define CAP     32      // max fast-path rows per ECC block (LDS x1buf)

typedef short short8 __attribute__((ext_vector_type(8)));
typedef float floatx4 __attribute__((ext_vector_type(4)));

__device__ __forceinline__ unsigned short f2bf(float f) {
    unsigned u = __float_as_uint(f);
    return (unsigned short)((u + 0x8000u) >> 16);   // RTN (ties up)
}
__device__ __forceinline__ float bf2f(unsigned short s) {
    return __uint_as_float(((unsigned)s) << 16);
}
// packed f32x2 -> bf16x2 (hardware v_cvt_pk_bf16_f32 on gfx950)
__device__ __forceinline__ unsigned pk2bf(float a, float b) {
    union { __hip_bfloat162 b2; unsigned u; } cv;
    cv.b2 = __float22bfloat162_rn(make_float2(a, b));
    return cv.u;
}

// ---------------------------------------------------------------------------
// 1) loc (+ one-time B3f prep in first 24 blocks): ONE returning atomic per
//    edge; local slot stored coalesced in loc[]. cnt ends as deg[].
// ---------------------------------------------------------------------------
__global__ __launch_bounds__(256) void loc_kernel(
    const int* __restrict__ ei, int E, int* __restrict__ cnt,
    int* __restrict__ loc,
    const float* __restrict__ w3, const float* __restrict__ b3,
    unsigned short* __restrict__ B3f)
{
    int i = blockIdx.x * 256 + threadIdx.x;
    if (i < 6144) {                      // fragment-ready B3 table
        int jj   = i & 7;
        int n    = (i >> 3) & 15;
        int quad = (i >> 7) & 3;
        int nt   = (i >> 9) & 1;
        int s    = i >> 10;
        int K = 32 * s + quad * 8 + jj;
        int o = n + 16 * nt;
        float v = 0.0f;
        if (o < N_OUTC) {
            if (K < 160)      v = w3[(K >> 3) * 160 + (K & 7) * N_OUTC + o];
            else if (K < 168) v = b3[(K - 160) * N_OUTC + o];
        }
        B3f[i] = f2bf(v);
    }
    if (i >= E) return;
    loc[i] = atomicAdd(&cnt[ei[i]], 1);
}

// ---------------------------------------------------------------------------
// 2a) Per-block sums of deg (coalesced)
// ---------------------------------------------------------------------------
__global__ __launch_bounds__(256) void scanA_kernel(
    const int* __restrict__ deg, int N, int* __restrict__ bsum)
{
    int i = blockIdx.x * 256 + threadIdx.x;
    int v = (i < N) ? deg[i] : 0;
#pragma unroll
    for (int d = 1; d < 64; d <<= 1) v += __shfl_down(v, d, 64);
    __shared__ int ws[4];
    int wid = threadIdx.x >> 6;
    if ((threadIdx.x & 63) == 0) ws[wid] = v;
    __syncthreads();
    if (threadIdx.x == 0) bsum[blockIdx.x] = ws[0] + ws[1] + ws[2] + ws[3];
}

// ---------------------------------------------------------------------------
// 2b) Apply: block offset from bsum, block-local scan -> rowptr; dinv
// ---------------------------------------------------------------------------
__global__ __launch_bounds__(256) void scanC_kernel(
    const int* __restrict__ deg, int N, const int* __restrict__ bsum, int nbl,
    int E, int* __restrict__ rowptr, float* __restrict__ dinv)
{
    __shared__ int ws[4];
    __shared__ int sboff;
    int t = threadIdx.x;
    {
        int v = (t < nbl && t < blockIdx.x) ? bsum[t] : 0;
#pragma unroll
        for (int d = 1; d < 64; d <<= 1) v += __shfl_down(v, d, 64);
        int wid = t >> 6;
        if ((t & 63) == 0) ws[wid] = v;
        __syncthreads();
        if (t == 0) sboff = ws[0] + ws[1] + ws[2] + ws[3];
        __syncthreads();
    }

    int i = blockIdx.x * 256 + t;
    int d0 = (i < N) ? deg[i] : 0;
    int v = d0;
#pragma unroll
    for (int d = 1; d < 64; d <<= 1) {
        int u = __shfl_up(v, d, 64);
        if ((t & 63) >= d) v += u;
    }
    __shared__ int ws2[4];
    int wid = t >> 6;
    if ((t & 63) == 63) ws2[wid] = v;
    __syncthreads();
    int woff = 0;
    for (int w = 0; w < wid; ++w) woff += ws2[w];
    if (i < N) {
        rowptr[i] = sboff + woff + v - d0;
        dinv[i] = rsqrtf((float)d0 + 1.0f);
    }
    if (blockIdx.x == 0 && t == 0) rowptr[N] = E;
}

// ---------------------------------------------------------------------------
// 3) Build slot-ordered edge records (NO atomics: p = rowptr[r] + loc[i]):
//    e_sorted[p] = {col:int, e[6]:bf16} = 16 B, one scattered store per edge.
// ---------------------------------------------------------------------------
__global__ __launch_bounds__(256) void build_kernel(
    const int* __restrict__ ei, int E, const float* __restrict__ e,
    const int* __restrict__ rowptr, const int* __restrict__ loc,
    int4* __restrict__ e_sorted)
{
    int i = blockIdx.x * 256 + threadIdx.x;
    if (i >= E) return;
    int r = ei[i];
    int c = ei[E + i];
    int p = rowptr[r] + loc[i];

    const float2* ep = (const float2*)&e[(size_t)i * S_DIM];   // 8B-aligned
    float2 e0 = ep[0], e1 = ep[1], e2 = ep[2];

    int4 rec;
    rec.x = c;
    rec.y = (int)pk2bf(e0.x, e0.y);
    rec.z = (int)pk2bf(e1.x, e1.y);
    rec.w = (int)pk2bf(e2.x, e2.y);
    e_sorted[p] = rec;
}

// ---------------------------------------------------------------------------
// 4) ECC: MLP (fp32 VALU) -> MFMA einsum -> segmented reduce WITH FUSED
//    node1 transform for fully-owned rows. Boundary/overflow -> agg+cleanup.
//    Packed bf16 conversion (v_cvt_pk_bf16_f32) in all hot cvt paths.
// ---------------------------------------------------------------------------
__global__ __launch_bounds__(256) void ecc_mfma_kernel(
    const int4* __restrict__ e_sorted, const float* __restrict__ x,
    const int* __restrict__ rowptr, int N, int E,
    const unsigned short* __restrict__ B3f,
    const float* __restrict__ w1, const float* __restrict__ b1,
    const float* __restrict__ w2, const float* __restrict__ b2,
    const float* __restrict__ root, const float* __restrict__ eb,
    const float* __restrict__ g1w,
    float* __restrict__ agg, int* __restrict__ col_sorted,
    unsigned short* __restrict__ hws1)
{
    __shared__ char smem[20480];
    __shared__ float x1buf[CAP * N_OUTC];   // 2.5 KB
    __shared__ int rbounds[2];
    unsigned short (*h2b)[N_OUTC] = (unsigned short (*)[N_OUTC])smem;          // 10240
    unsigned short (*xb)[F_INN]   = (unsigned short (*)[F_INN])(smem + 10240); // 4096
    float* lmsg = (float*)smem;                                                // 20480

    int t = threadIdx.x;
    int j0 = blockIdx.x * 256;
    int jend = min(j0 + 256, E);
    int j = j0 + t;

    if (t < 2) {
        int s = (t == 0) ? j0 : (jend - 1);
        int lo = 0, hi = N - 1;
        while (lo < hi) {
            int m = (lo + hi + 1) >> 1;
            if (rowptr[m] <= s) lo = m; else hi = m - 1;
        }
        rbounds[t] = lo;
    }

    // ---- per-edge MLP (fp32), 16B coalesced edge record load ----
    if (j < E) {
        int4 rec = e_sorted[j];
        int c = rec.x;
        col_sorted[j] = c;
        float ef[S_DIM] = {
            bf2f((unsigned short)(rec.y & 0xffff)),
            bf2f((unsigned short)((unsigned)rec.y >> 16)),
            bf2f((unsigned short)(rec.z & 0xffff)),
            bf2f((unsigned short)((unsigned)rec.z >> 16)),
            bf2f((unsigned short)(rec.w & 0xffff)),
            bf2f((unsigned short)((unsigned)rec.w >> 16))
        };

        float h1[H_DIM];
#pragma unroll
        for (int jj = 0; jj < H_DIM; ++jj) {
            float a = b1[jj];
#pragma unroll
            for (int s = 0; s < S_DIM; ++s) a = fmaf(ef[s], w1[s * H_DIM + jj], a);
            h1[jj] = fmaxf(a, 0.0f);
        }

        float h2[H_DIM];
#pragma unroll
        for (int jj = 0; jj < H_DIM; ++jj) {
            float a = b2[jj];
#pragma unroll
            for (int k = 0; k < H_DIM; ++k) a = fmaf(h1[k], w2[k * H_DIM + jj], a);
            h2[jj] = fmaxf(a, 0.0f);
        }

        const float4* xp = (const float4*)&x[(size_t)c * F_INN];
        float4 xa = xp[0], xb4 = xp[1];
        float xf[F_INN] = {xa.x, xa.y, xa.z, xa.w, xb4.x, xb4.y, xb4.z, xb4.w};

#pragma unroll
        for (int p = 0; p < N_OUTC / 2; ++p)
            *(unsigned*)&h2b[t][2 * p] = pk2bf(h2[2 * p], h2[2 * p + 1]);
#pragma unroll
        for (int p = 0; p < F_INN / 2; ++p)
            *(unsigned*)&xb[t][2 * p] = pk2bf(xf[2 * p], xf[2 * p + 1]);
    } else {
#pragma unroll
        for (int p = 0; p < N_OUTC / 2; ++p) *(unsigned*)&h2b[t][2 * p] = 0u;
#pragma unroll
        for (int p = 0; p < F_INN / 2; ++p)  *(unsigned*)&xb[t][2 * p] = 0u;
    }
    __syncthreads();

    // ---- B fragments straight from global (hot in L1 after block 0) ----
    int lane = t & 63;
    int quad = lane >> 4;
    int n = lane & 15;
    const short8* Bg = (const short8*)B3f;
    short8 Bf[12];
#pragma unroll
    for (int s = 0; s < 6; ++s)
#pragma unroll
        for (int nt = 0; nt < 2; ++nt)
            Bf[s * 2 + nt] = Bg[((s * 2 + nt) * 4 + quad) * 16 + n];

    // ---- MFMA: 4 m-tiles per wave, accs in registers ----
    int w = t >> 6;
    floatx4 acc0s[4], acc1s[4];
#pragma unroll
    for (int T = 0; T < 4; ++T) {
        int base = w * 64 + T * 16;
        int m = base + n;

        const short8 xv8 = *(const short8*)&xb[m][0];
        float xfl[F_INN];
#pragma unroll
        for (int jj = 0; jj < F_INN; ++jj) xfl[jj] = bf2f((unsigned short)xv8[jj]);

        floatx4 acc0 = {0.f, 0.f, 0.f, 0.f};
        floatx4 acc1 = {0.f, 0.f, 0.f, 0.f};
#pragma unroll
        for (int s = 0; s < 6; ++s) {
            short8 A = {0, 0, 0, 0, 0, 0, 0, 0};
            if (s < 5) {
                float h = bf2f(h2b[m][4 * s + quad]);
                union { short8 s8; unsigned u[4]; } av;
#pragma unroll
                for (int p = 0; p < 4; ++p)
                    av.u[p] = pk2bf(h * xfl[2 * p], h * xfl[2 * p + 1]);
                A = av.s8;
            } else if (quad == 0) {
                A = xv8;                        // b3 rows: p = x
            }
            acc0 = __builtin_amdgcn_mfma_f32_16x16x32_bf16(A, Bf[s * 2 + 0], acc0, 0, 0, 0);
            acc1 = __builtin_amdgcn_mfma_f32_16x16x32_bf16(A, Bf[s * 2 + 1], acc1, 0, 0, 0);
        }
        acc0s[T] = acc0;
        acc1s[T] = acc1;
    }
    __syncthreads();   // staging reads done -> lmsg may alias

    // ---- C-write: col = n (+16 for acc1), row = base + quad*4 + r ----
#pragma unroll
    for (int T = 0; T < 4; ++T) {
        int base = w * 64 + T * 16;
#pragma unroll
        for (int r = 0; r < 4; ++r) {
            int row = base + quad * 4 + r;
            lmsg[row * N_OUTC + n] = acc0s[T][r];
            if (n < 4) lmsg[row * N_OUTC + 16 + n] = acc1s[T][r];
        }
    }
    __syncthreads();

    // ---- R1: segmented reduce; fused root+bias+relu for fast rows ----
    int r0 = rbounds[0], r1 = rbounds[1];
    int nrows = r1 - r0 + 1;
    int work = nrows * 5;
    for (int ww = t; ww < work; ww += 256) {
        int idx = ww / 5;
        int q = ww - idx * 5;
        int row = r0 + idx;
        int a0 = rowptr[row], a1 = rowptr[row + 1];
        int s0 = max(a0, j0), s1 = min(a1, jend);
        float ac0 = 0.f, ac1 = 0.f, ac2 = 0.f, ac3 = 0.f;
        for (int s = s0; s < s1; ++s) {
            const float4 v = *(const float4*)&lmsg[(s - j0) * N_OUTC + q * 4];
            ac0 += v.x; ac1 += v.y; ac2 += v.z; ac3 += v.w;
        }
        bool owned = (a0 >= j0 && a1 <= jend);
        if (owned && idx < CAP) {
            const float4* xp = (const float4*)&x[(size_t)row * F_INN];
            float4 xa = xp[0], xb4 = xp[1];
            float rx[F_INN] = {xa.x, xa.y, xa.z, xa.w, xb4.x, xb4.y, xb4.z, xb4.w};
            float av[4] = {ac0, ac1, ac2, ac3};
#pragma unroll
            for (int u = 0; u < 4; ++u) {
                int oc = q * 4 + u;
                float a = av[u] + eb[oc];
#pragma unroll
                for (int f = 0; f < F_INN; ++f)
                    a = fmaf(rx[f], root[f * N_OUTC + oc], a);
                x1buf[idx * N_OUTC + oc] = fmaxf(a, 0.0f);
            }
        } else {
            float* dst = &agg[(size_t)row * N_OUTC + q * 4];
            if (owned) {
                *(float4*)dst = make_float4(ac0, ac1, ac2, ac3);
            } else {
                unsafeAtomicAdd(dst + 0, ac0);
                unsafeAtomicAdd(dst + 1, ac1);
                unsafeAtomicAdd(dst + 2, ac2);
                unsafeAtomicAdd(dst + 3, ac3);
            }
        }
    }
    __syncthreads();

    // ---- R2: hws1 = bf16(dinv * (x1 @ g1w)) for fast rows ----
    int fast = min(nrows, CAP);
    int work2 = fast * 8;
    for (int ww = t; ww < work2; ww += 256) {
        int idx = ww >> 3;
        int qc = ww & 7;
        int row = r0 + idx;
        int a0 = rowptr[row], a1 = rowptr[row + 1];
        if (!(a0 >= j0 && a1 <= jend)) continue;
        float di = rsqrtf((float)(a1 - a0) + 1.0f);
        float m0 = 0.f, m1 = 0.f, m2 = 0.f, m3 = 0.f;
        const float* xr = &x1buf[idx * N_OUTC];
#pragma unroll
        for (int o = 0; o < N_OUTC; ++o) {
            float xv = xr[o];
            const float4 g = *(const float4*)&g1w[o * G_DIM + qc * 4];
            m0 = fmaf(xv, g.x, m0); m1 = fmaf(xv, g.y, m1);
            m2 = fmaf(xv, g.z, m2); m3 = fmaf(xv, g.w, m3);
        }
        unsigned lo32 = pk2bf(m0 * di, m1 * di);
        unsigned hi32 = pk2bf(m2 * di, m3 * di);
        *(uint2*)&hws1[(size_t)row * G_DIM + qc * 4] = make_uint2(lo32, hi32);
    }
}

// ---------------------------------------------------------------------------
// 5) Cleanup: node transform for rows NOT handled by ECC's fast path.
// ---------------------------------------------------------------------------
__global__ __launch_bounds__(256) void cleanup_kernel(
    const float* __restrict__ agg, const float* __restrict__ x,
    const int* __restrict__ rowptr, int N,
    const float* __restrict__ root, const float* __restrict__ eb,
    const float* __restrict__ g1w,
    unsigned short* __restrict__ hws1)
{
    int n = blockIdx.x * 256 + threadIdx.x;
    if (n >= N) return;
    int a0 = rowptr[n], a1 = rowptr[n + 1];
    bool contained = (a1 > a0) ? ((a0 >> 8) == ((a1 - 1) >> 8))
                               : ((a0 & 255) != 0);
    if (contained) {
        int target = (a0 >> 8) << 8;
        int lo = 0, hi = N - 1;
        while (lo < hi) {
            int m = (lo + hi + 1) >> 1;
            if (rowptr[m] <= target) lo = m; else hi = m - 1;
        }
        if (n - lo < CAP) return;          // handled inside ECC
    }

    const float4* xp = (const float4*)&x[(size_t)n * F_INN];
    float4 xa = xp[0], xb = xp[1];
    float xf[F_INN] = {xa.x, xa.y, xa.z, xa.w, xb.x, xb.y, xb.z, xb.w};

    float x1[N_OUTC];
#pragma unroll
    for (int o = 0; o < N_OUTC; ++o) {
        float a = agg[(size_t)n * N_OUTC + o] + eb[o];
#pragma unroll
        for (int f = 0; f < F_INN; ++f) a = fmaf(xf[f], root[f * N_OUTC + o], a);
        x1[o] = fmaxf(a, 0.0f);
    }

    float di = rsqrtf((float)(a1 - a0) + 1.0f);
#pragma unroll
    for (int q = 0; q < 4; ++q) {
        float a[8];
#pragma unroll
        for (int u = 0; u < 8; ++u) {
            int g = q * 8 + u;
            float acc = 0.0f;
#pragma unroll
            for (int o = 0; o < N_OUTC; ++o) acc = fmaf(x1[o], g1w[o * G_DIM + g], acc);
            a[u] = acc * di;
        }
        union { short8 s8; unsigned u4[4]; } ov;
#pragma unroll
        for (int p = 0; p < 4; ++p) ov.u4[p] = pk2bf(a[2 * p], a[2 * p + 1]);
        *(short8*)&hws1[(size_t)n * G_DIM + q * 8] = ov.s8;
    }
}

// ---------------------------------------------------------------------------
// 6) GCN gather on pre-scaled bf16 features. Thread = (node, chunk of 4);
//    neighbor loop manually unrolled x4. DO_MATMUL: fused @W2 -> hws2 (bf16,
//    pre-scaled). Else: x3 (bf16, unscaled) for pool_head.
// ---------------------------------------------------------------------------
template<bool DO_MATMUL>
__global__ __launch_bounds__(256) void gcn_gather_kernel(
    const unsigned short* __restrict__ hws, const int* __restrict__ rowptr,
    const int* __restrict__ col_sorted, const float* __restrict__ dinv, int N,
    const float* __restrict__ bias, const float* __restrict__ w2,
    unsigned short* __restrict__ outbuf)
{
    __shared__ float x2s[DO_MATMUL ? 64 * 33 : 1];
    __shared__ float w2s[DO_MATMUL ? G_DIM * G_DIM : 1];

    int t = threadIdx.x;
    int nl = t >> 2;
    int q = t & 3;
    int n = blockIdx.x * 64 + nl;

    if (DO_MATMUL) {
        ((float4*)w2s)[t] = ((const float4*)w2)[t];
        __syncthreads();
    }

    float xo[8];
    float di = 0.0f;
    if (n < N) {
        di = dinv[n];
        int j0 = rowptr[n], j1 = rowptr[n + 1];
        short8 sv = *(const short8*)&hws[(size_t)n * G_DIM + q * 8];
        float s[8];
#pragma unroll
        for (int k = 0; k < 8; ++k) s[k] = bf2f((unsigned short)sv[k]);
        int j = j0;
        for (; j + 4 <= j1; j += 4) {
            int c0 = col_sorted[j + 0];
            int c1 = col_sorted[j + 1];
            int c2 = col_sorted[j + 2];
            int c3 = col_sorted[j + 3];
            short8 v0 = *(const short8*)&hws[(size_t)c0 * G_DIM + q * 8];
            short8 v1 = *(const short8*)&hws[(size_t)c1 * G_DIM + q * 8];
            short8 v2 = *(const short8*)&hws[(size_t)c2 * G_DIM + q * 8];
            short8 v3 = *(const short8*)&hws[(size_t)c3 * G_DIM + q * 8];
#pragma unroll
            for (int k = 0; k < 8; ++k)
                s[k] += (bf2f((unsigned short)v0[k]) + bf2f((unsigned short)v1[k]))
                      + (bf2f((unsigned short)v2[k]) + bf2f((unsigned short)v3[k]));
        }
        for (; j < j1; ++j) {
            int c = col_sorted[j];
            short8 v = *(const short8*)&hws[(size_t)c * G_DIM + q * 8];
#pragma unroll
            for (int k = 0; k < 8; ++k) s[k] += bf2f((unsigned short)v[k]);
        }
#pragma unroll
        for (int k = 0; k < 8; ++k)
            xo[k] = fmaxf(fmaf(di, s[k], bias[q * 8 + k]), 0.0f);
    } else {
#pragma unroll
        for (int k = 0; k < 8; ++k) xo[k] = 0.0f;
    }

    if (DO_MATMUL) {
#pragma unroll
        for (int k = 0; k < 8; ++k) x2s[nl * 33 + q * 8 + k] = xo[k];
        __syncthreads();
        if (n < N) {
            float a[8];
#pragma unroll
            for (int k = 0; k < 8; ++k) a[k] = 0.0f;
#pragma unroll
            for (int g = 0; g < G_DIM; ++g) {
                float xv = x2s[nl * 33 + g];
#pragma unroll
                for (int k = 0; k < 8; ++k)
                    a[k] = fmaf(xv, w2s[g * G_DIM + q * 8 + k], a[k]);
            }
            union { short8 s8; unsigned u4[4]; } ov;
#pragma unroll
            for (int p = 0; p < 4; ++p) ov.u4[p] = pk2bf(a[2 * p] * di, a[2 * p + 1] * di);
            *(short8*)&outbuf[(size_t)n * G_DIM + q * 8] = ov.s8;
        }
    } else {
        if (n < N) {
            union { short8 s8; unsigned u4[4]; } ov;
#pragma unroll
            for (int p = 0; p < 4; ++p) ov.u4[p] = pk2bf(xo[2 * p], xo[2 * p + 1]);
            *(short8*)&outbuf[(size_t)n * G_DIM + q * 8] = ov.s8;
        }
    }
}

// ---------------------------------------------------------------------------
// 7) Pool + head fused (x3 is bf16): block per graph, binary search on seg,
//    8x32 LDS reduce, head epilogue in wave 0.
// ---------------------------------------------------------------------------
__global__ __launch_bounds__(256) void pool_head_kernel(
    const unsigned short* __restrict__ x3, const int* __restrict__ seg, int N,
    const float* __restrict__ d1w, const float* __restrict__ d1b,
    const float* __restrict__ d2w, const float* __restrict__ d2b,
    float* __restrict__ out)
{
    __shared__ float red[8][G_DIM];
    __shared__ float pvec[G_DIM];
    __shared__ int bounds[2];
    int g = blockIdx.x;
    int t = threadIdx.x;
    if (t < 2) {
        int target = g + t;
        int lo = 0, hi = N;
        while (lo < hi) {
            int m = (lo + hi) >> 1;
            if (seg[m] < target) lo = m + 1; else hi = m;
        }
        bounds[t] = lo;
    }
    __syncthreads();
    int n0 = bounds[0], n1 = bounds[1];
    int ch = t & (G_DIM - 1);
    int slice = t >> 5;
    float a = 0.0f;
    for (int n = n0 + slice; n < n1; n += 8)
        a += bf2f(x3[(size_t)n * G_DIM + ch]);
    red[slice][ch] = a;
    __syncthreads();
    if (slice == 0) {
        float s = red[0][ch];
#pragma unroll
        for (int k = 1; k < 8; ++k) s += red[k][ch];
        pvec[ch] = s;
    }
    __syncthreads();
    if (t < 64) {
        float acc = 0.0f;
        if (t < D1_DIM) {
            float tj = d1b[t];
#pragma unroll
            for (int gg = 0; gg < G_DIM; ++gg)
                tj = fmaf(pvec[gg], d1w[gg * D1_DIM + t], tj);
            acc = tj * d2w[t];
        }
#pragma unroll
        for (int d = 1; d < D1_DIM; d <<= 1) acc += __shfl_down(acc, d, 64);
        if (t == 0) out[g] = acc + d2b[0];
    }
}

// ---------------------------------------------------------------------------
extern "C" void kernel_launch(void* const* d_in, const int* in_sizes, int n_in,
                              void* d_out, int out_size, void* d_ws, size_t ws_size,
                              hipStream_t stream)
{
    const float* x    = (const float*)d_in[0];
    const float* e    = (const float*)d_in[1];
    const int*   ei   = (const int*)d_in[2];
    const int*   seg  = (const int*)d_in[3];
    const float* w1   = (const float*)d_in[4];
    const float* b1   = (const float*)d_in[5];
    const float* w2   = (const float*)d_in[6];
    const float* b2   = (const float*)d_in[7];
    const float* w3   = (const float*)d_in[8];
    const float* b3   = (const float*)d_in[9];
    const float* root = (const float*)d_in[10];
    const float* eb   = (const float*)d_in[11];
    const float* g1w  = (const float*)d_in[12];
    const float* g1b  = (const float*)d_in[13];
    const float* g2w  = (const float*)d_in[14];
    const float* g2b  = (const float*)d_in[15];
    const float* d1w  = (const float*)d_in[16];
    const float* d1b  = (const float*)d_in[17];
    const float* d2w  = (const float*)d_in[18];
    const float* d2b  = (const float*)d_in[19];

    const int N = in_sizes[3];            // 50000
    const int E = in_sizes[1] / S_DIM;    // 800000
    float* out = (float*)d_out;

    const int nbl = (N + 255) / 256;      // 196 (<= 256 for scanC)
    const int ebl = (E + 255) / 256;

    char* ws = (char*)d_ws;
    size_t off = 0;
    auto alloc = [&](size_t elems) -> char* {
        char* p = ws + off;
        off += ((elems * 4 + 15) & ~(size_t)15);
        return p;
    };
    int*   cnt        = (int*)  alloc(N);                    // zeroed (deg)
    float* agg        = (float*)alloc((size_t)N * N_OUTC);   // zeroed
    size_t zero_bytes = off;
    int*   rowptr     = (int*)  alloc(N + 1);
    int*   bsum       = (int*)  alloc(nbl);
    float* dinv       = (float*)alloc(N);
    int*   loc        = (int*)  alloc(E);
    int*   col_sorted = (int*)  alloc(E);
    unsigned short* B3f = (unsigned short*)alloc(6144 / 2);  // 12.3 KB
    int4*  e_sorted   = (int4*) alloc((size_t)E * 4);        // 16 B/edge
    unsigned short* hws1 = (unsigned short*)alloc((size_t)N * G_DIM / 2);
    unsigned short* hws2 = (unsigned short*)alloc((size_t)N * G_DIM / 2);
    unsigned short* x3   = (unsigned short*)alloc((size_t)N * G_DIM / 2);
    (void)ws_size;

    hipMemsetAsync(d_ws, 0, zero_bytes, stream);

    loc_kernel<<<ebl, 256, 0, stream>>>(ei, E, cnt, loc, w3, b3, B3f);
    scanA_kernel<<<nbl, 256, 0, stream>>>(cnt, N, bsum);
    scanC_kernel<<<nbl, 256, 0, stream>>>(cnt, N, bsum, nbl, E, rowptr, dinv);
    build_kernel<<<ebl, 256, 0, stream>>>(ei, E, e, rowptr, loc, e_sorted);
    ecc_mfma_kernel<<<ebl, 256, 0, stream>>>(e_sorted, x, rowptr, N, E, B3f,
                                             w1, b1, w2, b2, root, eb, g1w,
                                             agg, col_sorted, hws1);
    cleanup_kernel<<<nbl, 256, 0, stream>>>(agg, x, rowptr, N, root, eb, g1w, hws1);
    gcn_gather_kernel<true><<<(N + 63) / 64, 256, 0, stream>>>(
        hws1, rowptr, col_sorted, dinv, N, g1b, g2w, hws2);
    gcn_gather_kernel<false><<<(N + 63) / 64, 256, 0, stream>>>(
        hws2, rowptr, col_sorted, dinv, N, g2b, nullptr, x3);
    pool_head_kernel<<<NGRAPH, 256, 0, stream>>>(x3, seg, N, d1w, d1b, d2w, d2b, out);
}